// Round 1
// baseline (30.928 us; speedup 1.0000x reference)
//
#include <hip/hip_runtime.h>

constexpr int KSZ     = 16;
constexpr int STRIDE  = 4;
constexpr int NROWS   = 4096;
constexpr int LCOLS   = 8192;
constexpr int OUT_LEN = (LCOLS - KSZ) / STRIDE + 1;  // 2045

__global__ __launch_bounds__(256) void or_conv_kernel(
    const float* __restrict__ x, const float* __restrict__ w,
    float* __restrict__ out)
{
    const int o = blockIdx.x * 256 + threadIdx.x;
    const int n = blockIdx.y;
    if (o >= OUT_LEN) return;

    // Weights: wave-uniform address, constant index -> SGPR scalar loads.
    float wr[KSZ];
#pragma unroll
    for (int k = 0; k < KSZ; ++k) wr[k] = w[k];

    // Window start = o*4 floats = 16B aligned -> four aligned float4 loads.
    const float4* p = reinterpret_cast<const float4*>(
        x + (size_t)n * LCOLS + (size_t)o * STRIDE);
    float4 a[4];
#pragma unroll
    for (int j = 0; j < 4; ++j) a[j] = p[j];

    const float* win = reinterpret_cast<const float*>(a);

    // rho bounded (|x|<~6, w<=0.7 -> rho<~4.2): exp never overflows,
    // skip the max-subtraction (mathematically identical result).
    float se = 0.f, sr = 0.f;
#pragma unroll
    for (int k = 0; k < KSZ; ++k) {
        float rho = win[k] * wr[k];
        float e   = __expf(rho);
        se += e;
        sr  = fmaf(rho, e, sr);
    }

    out[(size_t)n * OUT_LEN + o] = sr / se;
}

extern "C" void kernel_launch(void* const* d_in, const int* in_sizes, int n_in,
                              void* d_out, int out_size, void* d_ws, size_t ws_size,
                              hipStream_t stream)
{
    const float* x = (const float*)d_in[0];
    const float* w = (const float*)d_in[1];
    float* out     = (float*)d_out;

    dim3 block(256);
    dim3 grid((OUT_LEN + 255) / 256, NROWS);
    or_conv_kernel<<<grid, block, 0, stream>>>(x, w, out);
}